// Round 5
// baseline (292.535 us; speedup 1.0000x reference)
//
#include <hip/hip_runtime.h>
#include <hip/hip_bf16.h>
#include <math.h>

// Problem constants: T=2048, B=2, E=1024, H=16, d=64
constexpr int T_DIM = 2048;
constexpr int B_DIM = 2;
constexpr int E_DIM = 1024;
constexpr float SCALE = 0.125f;  // d^-0.5

typedef __attribute__((ext_vector_type(8))) short short8;   // 8 x bf16 (4 VGPRs)
typedef __attribute__((ext_vector_type(4))) float f32x4;    // MFMA C/D frag

__device__ inline short f2bf(float x) {
    union { __hip_bfloat16 b; short s; } u;
    u.b = __float2bfloat16(x);
    return u.s;
}
__device__ inline float bf2f(short s) {
    union { __hip_bfloat16 b; short s; } u;
    u.s = s;
    return __bfloat162float(u.b);
}

__device__ inline void gl2lds16(const void* g, void* l) {
    __builtin_amdgcn_global_load_lds(
        (const __attribute__((address_space(1))) unsigned int*)g,
        (__attribute__((address_space(3))) unsigned int*)l, 16, 0, 0);
}

__device__ inline f32x4 mfma_bf16(short8 a, short8 b, f32x4 c) {
    return __builtin_amdgcn_mfma_f32_16x16x32_bf16(a, b, c, 0, 0, 0);
}

// ---------------------------------------------------------------------------
// split fp32 -> bf16 hi (+ optional lo residual). n4 = n/4 float4 chunks.
// ---------------------------------------------------------------------------
__global__ __launch_bounds__(256)
void split_bf16_kernel(const float* __restrict__ x, short* __restrict__ h,
                       short* __restrict__ l, int n4, int do_lo)
{
    int i = blockIdx.x * 256 + threadIdx.x;
    if (i >= n4) return;
    float4 v = ((const float4*)x)[i];
    short h0 = f2bf(v.x), h1 = f2bf(v.y), h2 = f2bf(v.z), h3 = f2bf(v.w);
    ((short4*)h)[i] = make_short4(h0, h1, h2, h3);
    if (do_lo) {
        short l0 = f2bf(v.x - bf2f(h0));
        short l1 = f2bf(v.y - bf2f(h1));
        short l2 = f2bf(v.z - bf2f(h2));
        short l3 = f2bf(v.w - bf2f(h3));
        ((short4*)l)[i] = make_short4(l0, l1, l2, l3);
    }
}

// ---------------------------------------------------------------------------
// C[M][N] = A[M][K] @ W[N][K]^T + bias via bf16 MFMA, error-compensated
// splits.  (unchanged — verified r2-r4)
// ---------------------------------------------------------------------------
template <bool ALO, bool BF16OUT>
__global__ __launch_bounds__(256)
void gemm_mfma(const short* __restrict__ Ah, const short* __restrict__ Al,
               const short* __restrict__ Wh, const short* __restrict__ Wl,
               const float* __restrict__ bias, void* __restrict__ Cout,
               int M, int N, int K)
{
    __shared__ __align__(16) short AsH[128 * 32];
    __shared__ __align__(16) short AsL[ALO ? 128 * 32 : 8];
    __shared__ __align__(16) short WsH[128 * 32];
    __shared__ __align__(16) short WsL[128 * 32];

    const int tid  = threadIdx.x;
    const int lane = tid & 63;
    const int wave = tid >> 6;
    const int rm = (wave >> 1) * 64;
    const int cn = (wave & 1) * 64;
    const int m0 = blockIdx.y * 128;
    const int n0 = blockIdx.x * 128;

    const int srow0 = wave * 32 + (lane >> 2);
    const int srow1 = srow0 + 16;
    const int p4 = lane & 3;
    const int kc0 = p4 ^ ((srow0 >> 1) & 3);
    const int kc1 = p4 ^ ((srow1 >> 1) & 3);

    short* ldsA0 = &AsH[(wave * 32) * 32];
    short* ldsA1 = &AsH[(wave * 32 + 16) * 32];
    short* ldsAl0 = &AsL[ALO ? (wave * 32) * 32 : 0];
    short* ldsAl1 = &AsL[ALO ? (wave * 32 + 16) * 32 : 0];
    short* ldsW0 = &WsH[(wave * 32) * 32];
    short* ldsW1 = &WsH[(wave * 32 + 16) * 32];
    short* ldsWl0 = &WsL[(wave * 32) * 32];
    short* ldsWl1 = &WsL[(wave * 32 + 16) * 32];

    const size_t ga0 = (size_t)(m0 + srow0) * K + kc0 * 8;
    const size_t ga1 = (size_t)(m0 + srow1) * K + kc1 * 8;
    const size_t gw0 = (size_t)(n0 + srow0) * K + kc0 * 8;
    const size_t gw1 = (size_t)(n0 + srow1) * K + kc1 * 8;

    const f32x4 zero = {0.f, 0.f, 0.f, 0.f};
    f32x4 acc[4][4];
    #pragma unroll
    for (int i = 0; i < 4; ++i)
        #pragma unroll
        for (int j = 0; j < 4; ++j) acc[i][j] = zero;

    const int fr = lane & 15;
    const int qc = lane >> 4;

    for (int k0 = 0; k0 < K; k0 += 32) {
        if (k0) __syncthreads();
        gl2lds16(Ah + ga0 + k0, ldsA0);
        gl2lds16(Ah + ga1 + k0, ldsA1);
        if constexpr (ALO) {
            gl2lds16(Al + ga0 + k0, ldsAl0);
            gl2lds16(Al + ga1 + k0, ldsAl1);
        }
        gl2lds16(Wh + gw0 + k0, ldsW0);
        gl2lds16(Wh + gw1 + k0, ldsW1);
        gl2lds16(Wl + gw0 + k0, ldsWl0);
        gl2lds16(Wl + gw1 + k0, ldsWl1);
        __syncthreads();

        short8 ahf[4], alf[4], bhf[4], blf[4];
        #pragma unroll
        for (int i = 0; i < 4; ++i) {
            int r = rm + 16 * i + fr;
            int slot = qc ^ ((r >> 1) & 3);
            ahf[i] = *(const short8*)&AsH[r * 32 + slot * 8];
            if constexpr (ALO) alf[i] = *(const short8*)&AsL[r * 32 + slot * 8];
        }
        #pragma unroll
        for (int j = 0; j < 4; ++j) {
            int r = cn + 16 * j + fr;
            int slot = qc ^ ((r >> 1) & 3);
            bhf[j] = *(const short8*)&WsH[r * 32 + slot * 8];
            blf[j] = *(const short8*)&WsL[r * 32 + slot * 8];
        }
        #pragma unroll
        for (int i = 0; i < 4; ++i)
            #pragma unroll
            for (int j = 0; j < 4; ++j) {
                acc[i][j] = mfma_bf16(ahf[i], bhf[j], acc[i][j]);
                acc[i][j] = mfma_bf16(ahf[i], blf[j], acc[i][j]);
                if constexpr (ALO)
                    acc[i][j] = mfma_bf16(alf[i], bhf[j], acc[i][j]);
            }
    }

    const int g = lane >> 4;
    #pragma unroll
    for (int j = 0; j < 4; ++j) {
        int col = n0 + cn + 16 * j + fr;
        float bj = bias[col];
        #pragma unroll
        for (int i = 0; i < 4; ++i)
            #pragma unroll
            for (int r = 0; r < 4; ++r) {
                int row = m0 + rm + 16 * i + g * 4 + r;
                float v = acc[i][j][r] + bj;
                if constexpr (BF16OUT)
                    ((short*)Cout)[(size_t)row * N + col] = f2bf(v);
                else
                    ((float*)Cout)[(size_t)row * N + col] = v;
            }
    }
}

// ---------------------------------------------------------------------------
// One-shot V transpose: qkv [t][b][h*192+128+dd]  ->  vtp [bh][dd][t].
// Block = (t-tile 64, bh). LDS transpose: b16 scatter writes are
// conflict-free (dd fixed per instr, m spans all banks), b128 reads ~2-way.
// ---------------------------------------------------------------------------
__global__ __launch_bounds__(256)
void repack_vt(const short* __restrict__ qkv, short* __restrict__ vtp)
{
    __shared__ __align__(16) short Vl[64 * 72];   // [dd][t_local], pitch 72

    const int tid = threadIdx.x;
    const int t0 = blockIdx.x * 64;
    const int bh = blockIdx.y;
    const int b = bh >> 4, h = bh & 15;
    const int wv = tid >> 6;        // wave selects chunk pair
    const int m  = tid & 63;        // t row within tile

    const short* src = qkv + ((size_t)(t0 + m) * 2 + b) * 3072 + h * 192 + 128;
    short8 v0 = *(const short8*)(src + (2 * wv) * 8);
    short8 v1 = *(const short8*)(src + (2 * wv + 1) * 8);
    #pragma unroll
    for (int j = 0; j < 8; ++j) {
        Vl[(wv * 16 + j) * 72 + m]     = v0[j];
        Vl[(wv * 16 + 8 + j) * 72 + m] = v1[j];
    }
    __syncthreads();

    const int dd = tid >> 2;
    const int oc = tid & 3;
    uint4 w0 = *(const uint4*)&Vl[dd * 72 + oc * 16];
    uint4 w1 = *(const uint4*)&Vl[dd * 72 + oc * 16 + 8];
    short* dst = vtp + (size_t)bh * (64 * 2048) + (size_t)dd * 2048 + t0 + oc * 16;
    *(uint4*)(dst) = w0;
    *(uint4*)(dst + 8) = w1;
}

// ---------------------------------------------------------------------------
// Flash attention v5.
//  * 512 blocks (128-row Q tile x bh), 4 waves; each wave: 32 q rows as
//    TWO 16-row sets sharing every K/V fragment read (2x FLOP per read).
//  * S^T + key-permutation trick (r4-verified): exp'd C-frags ARE the PV
//    A-frags, zero P LDS traffic.
//  * V fragments read directly from global vtp (L2-resident) — no V LDS.
//  * Ks double-buffered, ONE barrier per iter; K tile reg-prefetched.
//  * l-sum in VALU (lane's C-regs are one q-column); 2 shfls at the end.
// ---------------------------------------------------------------------------
__global__ __launch_bounds__(256)
void attn_mfma(const short* __restrict__ qkv, const short* __restrict__ vtp,
               short* __restrict__ ctxh, short* __restrict__ ctxl)
{
    __shared__ __align__(16) short Ks[2][64 * 72];  // [buf][perm key row][d]
    __shared__ float Ls[4][32];

    const int tid  = threadIdx.x;
    const int lane = tid & 63;
    const int wave = tid >> 6;
    const int fr = lane & 15;
    const int g  = lane >> 4;

    // XCD-aware decode: 8 XCDs x 4 bh x 16 q-tiles
    const int id   = blockIdx.x;
    const int slot = id >> 3;
    const int bh   = (id & 7) * 4 + (slot & 3);
    const int q0   = (slot >> 2) * 128;
    const int b = bh >> 4, h = bh & 15;

    const int mrow = tid >> 3;   // staged key row 0..31 (+32)
    const int c8   = tid & 7;
    const int R0 = (((mrow >> 2) & 1) << 4) | (((mrow >> 3) & 3) << 2) | (mrow & 3);

    // ---- Q fragments: 2 sets of 16 rows, straight from global ----
    short8 aq[2][2];
    #pragma unroll
    for (int set = 0; set < 2; ++set) {
        const short* qrow = qkv +
            ((size_t)(q0 + wave * 32 + set * 16 + fr) * 2 + b) * 3072 + h * 192;
        aq[set][0] = *(const short8*)(qrow + g * 8);
        aq[set][1] = *(const short8*)(qrow + 32 + g * 8);
    }

    const short* vbase = vtp + (size_t)bh * (64 * 2048);

    const f32x4 zero = {0.f, 0.f, 0.f, 0.f};
    f32x4 o[2][4];
    #pragma unroll
    for (int set = 0; set < 2; ++set)
        #pragma unroll
        for (int jd = 0; jd < 4; ++jd) o[set][jd] = zero;
    float lsum[2] = {0.f, 0.f};

    // ---- prefetch first K tile into registers ----
    uint4 kreg[2];
    #pragma unroll
    for (int rr = 0; rr < 2; ++rr) {
        int t = mrow + 32 * rr;
        kreg[rr] = *(const uint4*)(qkv + ((size_t)t * 2 + b) * 3072 + h * 192 + 64 + c8 * 8);
    }

    for (int s0 = 0; s0 < T_DIM; s0 += 64) {
        const int p = (s0 >> 6) & 1;
        // write this tile (safe: buf p last read 2 iters ago, proven by barrier chain)
        *(uint4*)&Ks[p][(R0     ) * 72 + c8 * 8] = kreg[0];
        *(uint4*)&Ks[p][(R0 + 32) * 72 + c8 * 8] = kreg[1];
        __syncthreads();   // single barrier per iter

        if (s0 + 64 < T_DIM) {   // prefetch next K tile (overlaps compute)
            #pragma unroll
            for (int rr = 0; rr < 2; ++rr) {
                int t = s0 + 64 + mrow + 32 * rr;
                kreg[rr] = *(const uint4*)(qkv + ((size_t)t * 2 + b) * 3072 + h * 192 + 64 + c8 * 8);
            }
        }
        // V fragments for this tile: direct from global (L2)
        short8 bv0[4], bv1[4];
        #pragma unroll
        for (int jd = 0; jd < 4; ++jd) {
            const short* vr = vbase + (size_t)(16 * jd + fr) * 2048 + s0 + g * 8;
            bv0[jd] = *(const short8*)vr;
            bv1[jd] = *(const short8*)(vr + 32);
        }

        // ---- S^T = K Q^T, exp -> register A-frags (both q-sets) ----
        short8 af[2][2];
        #pragma unroll
        for (int s = 0; s < 4; ++s) {
            short8 bk0 = *(const short8*)&Ks[p][(16 * s + fr) * 72 + g * 8];
            short8 bk1 = *(const short8*)&Ks[p][(16 * s + fr) * 72 + 32 + g * 8];
            #pragma unroll
            for (int set = 0; set < 2; ++set) {
                f32x4 a = zero;
                a = mfma_bf16(bk0, aq[set][0], a);
                a = mfma_bf16(bk1, aq[set][1], a);
                #pragma unroll
                for (int r = 0; r < 4; ++r) {
                    short pb = f2bf(__expf(a[r] * SCALE));   // bounded arg
                    lsum[set] += bf2f(pb);
                    if (s < 2) af[set][0][(s & 1) * 4 + r] = pb;
                    else       af[set][1][(s & 1) * 4 + r] = pb;
                }
            }
        }

        // ---- O += P V (register P, global-loaded V) ----
        #pragma unroll
        for (int set = 0; set < 2; ++set)
            #pragma unroll
            for (int jd = 0; jd < 4; ++jd) {
                o[set][jd] = mfma_bf16(af[set][0], bv0[jd], o[set][jd]);
                o[set][jd] = mfma_bf16(af[set][1], bv1[jd], o[set][jd]);
            }
    }

    // ---- finalize l: combine the 4 g-partials per q-column ----
    #pragma unroll
    for (int set = 0; set < 2; ++set) {
        lsum[set] += __shfl_xor(lsum[set], 16);
        lsum[set] += __shfl_xor(lsum[set], 32);
        Ls[wave][set * 16 + fr] = lsum[set];   // 4 dup writes, same value
    }
    __builtin_amdgcn_s_waitcnt(0xc07f);   // lgkmcnt(0): wave-private Ls visible

    // ---- epilogue: normalize, split hi/lo, store ctx ----
    #pragma unroll
    for (int set = 0; set < 2; ++set)
        #pragma unroll
        for (int r = 0; r < 4; ++r) {
            float inv = 1.f / Ls[wave][set * 16 + 4 * g + r];
            int t = q0 + wave * 32 + set * 16 + 4 * g + r;
            size_t base = ((size_t)t * B_DIM + b) * E_DIM + h * 64;
            #pragma unroll
            for (int jd = 0; jd < 4; ++jd) {
                float v = o[set][jd][r] * inv;
                short hs = f2bf(v);
                short ls = f2bf(v - bf2f(hs));
                ctxh[base + 16 * jd + fr] = hs;
                ctxl[base + 16 * jd + fr] = ls;
            }
        }
}

// ---------------------------------------------------------------------------
extern "C" void kernel_launch(void* const* d_in, const int* in_sizes, int n_in,
                              void* d_out, int out_size, void* d_ws, size_t ws_size,
                              hipStream_t stream)
{
    const float* query = (const float*)d_in[0];
    const float* w_in  = (const float*)d_in[1];
    const float* b_in  = (const float*)d_in[2];
    const float* w_out = (const float*)d_in[3];
    const float* b_out = (const float*)d_in[4];
    float* out = (float*)d_out;

    char* ws = (char*)d_ws;
    short* qkv  = (short*)(ws);                  // 25.2 MB
    short* qh   = (short*)(ws + 25165824);       // 8.4 MB
    short* wih  = (short*)(ws + 33554432);       // 6.3 MB
    short* wil  = (short*)(ws + 39845888);       // 6.3 MB
    short* woh  = (short*)(ws + 46137344);       // 2.1 MB
    short* wol  = (short*)(ws + 48234496);       // 2.1 MB
    short* vtp  = (short*)(ws + 50331648);       // 8.4 MB  V^T [bh][d][t]
    short* ctxh = (short*)(ws + 25165824);       // alias qh  (dead after in_proj)
    short* ctxl = (short*)(ws + 33554432);       // alias wih (dead after in_proj)

    const int M = T_DIM * B_DIM;  // 4096

    int nq4  = (M * E_DIM) / 4;
    int nwi4 = (3 * E_DIM * E_DIM) / 4;
    int nwo4 = (E_DIM * E_DIM) / 4;
    split_bf16_kernel<<<nq4 / 256, 256, 0, stream>>>(query, qh, nullptr, nq4, 0);
    split_bf16_kernel<<<nwi4 / 256, 256, 0, stream>>>(w_in, wih, wil, nwi4, 1);
    split_bf16_kernel<<<nwo4 / 256, 256, 0, stream>>>(w_out, woh, wol, nwo4, 1);

    // in_proj: qkv_bf16 = q @ w_in^T + b_in   (w-split, 2 MFMA)
    gemm_mfma<false, true><<<dim3(3 * E_DIM / 128, M / 128), 256, 0, stream>>>(
        qh, qh, wih, wil, b_in, qkv, M, 3 * E_DIM, E_DIM);

    // one-shot V transpose into [bh][d][t]
    repack_vt<<<dim3(T_DIM / 64, 32), 256, 0, stream>>>(qkv, vtp);

    // attention: 512 blocks (128-q tiles), XCD-swizzled decode in-kernel
    attn_mfma<<<dim3(512), 256, 0, stream>>>(qkv, vtp, ctxh, ctxl);

    // out_proj: out = ctx @ w_out^T + b_out   (full split, 3 MFMA)
    gemm_mfma<true, false><<<dim3(E_DIM / 128, M / 128), 256, 0, stream>>>(
        ctxh, ctxl, woh, wol, b_out, out, M, E_DIM, E_DIM);
}

// Round 6
// 291.844 us; speedup vs baseline: 1.0024x; 1.0024x over previous
//
#include <hip/hip_runtime.h>
#include <hip/hip_bf16.h>
#include <math.h>

// Problem constants: T=2048, B=2, E=1024, H=16, d=64
constexpr int T_DIM = 2048;
constexpr int B_DIM = 2;
constexpr int E_DIM = 1024;
// Q pre-scale folded into in_proj epilogue: d^-0.5 * log2(e); attention then
// computes p = exp2(s_scaled) = exp(s_orig * d^-0.5).
constexpr float QK_SCALE = 0.18033688011112042f;

#if __has_builtin(__builtin_amdgcn_exp2f)
#define EXP2F(x) __builtin_amdgcn_exp2f(x)
#else
#define EXP2F(x) exp2f(x)
#endif

typedef __attribute__((ext_vector_type(8))) short short8;   // 8 x bf16 (4 VGPRs)
typedef __attribute__((ext_vector_type(4))) float f32x4;    // MFMA C/D frag

__device__ inline short f2bf(float x) {
    union { __hip_bfloat16 b; short s; } u;
    u.b = __float2bfloat16(x);
    return u.s;
}
__device__ inline float bf2f(short s) {
    union { __hip_bfloat16 b; short s; } u;
    u.s = s;
    return __bfloat162float(u.b);
}

// pack two positive f32 to bf16 pair (lo in low half), round-to-nearest
// (ties away) via +0x8000 then v_perm grabbing high halves.
__device__ inline int pack_bf16(float hi, float lo) {
    union { float f; unsigned u; } a, b;
    a.f = hi; b.f = lo;
    return (int)__builtin_amdgcn_perm(a.u + 0x8000u, b.u + 0x8000u, 0x07060302u);
}

__device__ inline void gl2lds16(const void* g, void* l) {
    __builtin_amdgcn_global_load_lds(
        (const __attribute__((address_space(1))) unsigned int*)g,
        (__attribute__((address_space(3))) unsigned int*)l, 16, 0, 0);
}

__device__ inline f32x4 mfma_bf16(short8 a, short8 b, f32x4 c) {
    return __builtin_amdgcn_mfma_f32_16x16x32_bf16(a, b, c, 0, 0, 0);
}

// ---------------------------------------------------------------------------
// Fused split: query (hi only), w_in (hi+lo), w_out (hi+lo). One launch.
// ---------------------------------------------------------------------------
__global__ __launch_bounds__(256)
void split_all_kernel(const float* __restrict__ query,
                      const float* __restrict__ w_in,
                      const float* __restrict__ w_out,
                      short* __restrict__ qh,
                      short* __restrict__ wih, short* __restrict__ wil,
                      short* __restrict__ woh, short* __restrict__ wol,
                      int nq4, int nwi4, int nwo4)
{
    int i = blockIdx.x * 256 + threadIdx.x;
    const float* src; short* dh; short* dl; int k; int do_lo;
    if (i < nq4) { src = query; dh = qh; dl = nullptr; k = i; do_lo = 0; }
    else if (i < nq4 + nwi4) { src = w_in; dh = wih; dl = wil; k = i - nq4; do_lo = 1; }
    else { src = w_out; dh = woh; dl = wol; k = i - nq4 - nwi4; do_lo = 1; }
    float4 v = ((const float4*)src)[k];
    short h0 = f2bf(v.x), h1 = f2bf(v.y), h2 = f2bf(v.z), h3 = f2bf(v.w);
    ((short4*)dh)[k] = make_short4(h0, h1, h2, h3);
    if (do_lo) {
        short l0 = f2bf(v.x - bf2f(h0));
        short l1 = f2bf(v.y - bf2f(h1));
        short l2 = f2bf(v.z - bf2f(h2));
        short l3 = f2bf(v.w - bf2f(h3));
        ((short4*)dl)[k] = make_short4(l0, l1, l2, l3);
    }
}

// ---------------------------------------------------------------------------
// C[M][N] = A[M][K] @ W[N][K]^T + bias via bf16 MFMA, error-compensated
// splits.  QSC: pre-scale q-columns (f>>6 % 3 == 0) by QK_SCALE for the
// attention exp2 path.  (core verified r2-r5)
// ---------------------------------------------------------------------------
template <bool ALO, bool BF16OUT, bool QSC>
__global__ __launch_bounds__(256)
void gemm_mfma(const short* __restrict__ Ah, const short* __restrict__ Al,
               const short* __restrict__ Wh, const short* __restrict__ Wl,
               const float* __restrict__ bias, void* __restrict__ Cout,
               int M, int N, int K)
{
    __shared__ __align__(16) short AsH[128 * 32];
    __shared__ __align__(16) short AsL[ALO ? 128 * 32 : 8];
    __shared__ __align__(16) short WsH[128 * 32];
    __shared__ __align__(16) short WsL[128 * 32];

    const int tid  = threadIdx.x;
    const int lane = tid & 63;
    const int wave = tid >> 6;
    const int rm = (wave >> 1) * 64;
    const int cn = (wave & 1) * 64;
    const int m0 = blockIdx.y * 128;
    const int n0 = blockIdx.x * 128;

    const int srow0 = wave * 32 + (lane >> 2);
    const int srow1 = srow0 + 16;
    const int p4 = lane & 3;
    const int kc0 = p4 ^ ((srow0 >> 1) & 3);
    const int kc1 = p4 ^ ((srow1 >> 1) & 3);

    short* ldsA0 = &AsH[(wave * 32) * 32];
    short* ldsA1 = &AsH[(wave * 32 + 16) * 32];
    short* ldsAl0 = &AsL[ALO ? (wave * 32) * 32 : 0];
    short* ldsAl1 = &AsL[ALO ? (wave * 32 + 16) * 32 : 0];
    short* ldsW0 = &WsH[(wave * 32) * 32];
    short* ldsW1 = &WsH[(wave * 32 + 16) * 32];
    short* ldsWl0 = &WsL[(wave * 32) * 32];
    short* ldsWl1 = &WsL[(wave * 32 + 16) * 32];

    const size_t ga0 = (size_t)(m0 + srow0) * K + kc0 * 8;
    const size_t ga1 = (size_t)(m0 + srow1) * K + kc1 * 8;
    const size_t gw0 = (size_t)(n0 + srow0) * K + kc0 * 8;
    const size_t gw1 = (size_t)(n0 + srow1) * K + kc1 * 8;

    const f32x4 zero = {0.f, 0.f, 0.f, 0.f};
    f32x4 acc[4][4];
    #pragma unroll
    for (int i = 0; i < 4; ++i)
        #pragma unroll
        for (int j = 0; j < 4; ++j) acc[i][j] = zero;

    const int fr = lane & 15;
    const int qc = lane >> 4;

    for (int k0 = 0; k0 < K; k0 += 32) {
        if (k0) __syncthreads();
        gl2lds16(Ah + ga0 + k0, ldsA0);
        gl2lds16(Ah + ga1 + k0, ldsA1);
        if constexpr (ALO) {
            gl2lds16(Al + ga0 + k0, ldsAl0);
            gl2lds16(Al + ga1 + k0, ldsAl1);
        }
        gl2lds16(Wh + gw0 + k0, ldsW0);
        gl2lds16(Wh + gw1 + k0, ldsW1);
        gl2lds16(Wl + gw0 + k0, ldsWl0);
        gl2lds16(Wl + gw1 + k0, ldsWl1);
        __syncthreads();

        short8 ahf[4], alf[4], bhf[4], blf[4];
        #pragma unroll
        for (int i = 0; i < 4; ++i) {
            int r = rm + 16 * i + fr;
            int slot = qc ^ ((r >> 1) & 3);
            ahf[i] = *(const short8*)&AsH[r * 32 + slot * 8];
            if constexpr (ALO) alf[i] = *(const short8*)&AsL[r * 32 + slot * 8];
        }
        #pragma unroll
        for (int j = 0; j < 4; ++j) {
            int r = cn + 16 * j + fr;
            int slot = qc ^ ((r >> 1) & 3);
            bhf[j] = *(const short8*)&WsH[r * 32 + slot * 8];
            blf[j] = *(const short8*)&WsL[r * 32 + slot * 8];
        }
        #pragma unroll
        for (int i = 0; i < 4; ++i)
            #pragma unroll
            for (int j = 0; j < 4; ++j) {
                acc[i][j] = mfma_bf16(ahf[i], bhf[j], acc[i][j]);
                acc[i][j] = mfma_bf16(ahf[i], blf[j], acc[i][j]);
                if constexpr (ALO)
                    acc[i][j] = mfma_bf16(alf[i], bhf[j], acc[i][j]);
            }
    }

    const int g = lane >> 4;
    #pragma unroll
    for (int j = 0; j < 4; ++j) {
        int col = n0 + cn + 16 * j + fr;
        float bj = bias[col];
        float cs = 1.0f;
        if constexpr (QSC) cs = (((col >> 6) % 3) == 0) ? QK_SCALE : 1.0f;
        #pragma unroll
        for (int i = 0; i < 4; ++i)
            #pragma unroll
            for (int r = 0; r < 4; ++r) {
                int row = m0 + rm + 16 * i + g * 4 + r;
                float v = (acc[i][j][r] + bj) * cs;
                if constexpr (BF16OUT)
                    ((short*)Cout)[(size_t)row * N + col] = f2bf(v);
                else
                    ((float*)Cout)[(size_t)row * N + col] = v;
            }
    }
}

// ---------------------------------------------------------------------------
// One-shot V transpose: qkv [t][b][h*192+128+dd]  ->  vtp [bh][dd][t].
// (verified r5)
// ---------------------------------------------------------------------------
__global__ __launch_bounds__(256)
void repack_vt(const short* __restrict__ qkv, short* __restrict__ vtp)
{
    __shared__ __align__(16) short Vl[64 * 72];

    const int tid = threadIdx.x;
    const int t0 = blockIdx.x * 64;
    const int bh = blockIdx.y;
    const int b = bh >> 4, h = bh & 15;
    const int wv = tid >> 6;
    const int m  = tid & 63;

    const short* src = qkv + ((size_t)(t0 + m) * 2 + b) * 3072 + h * 192 + 128;
    short8 v0 = *(const short8*)(src + (2 * wv) * 8);
    short8 v1 = *(const short8*)(src + (2 * wv + 1) * 8);
    #pragma unroll
    for (int j = 0; j < 8; ++j) {
        Vl[(wv * 16 + j) * 72 + m]     = v0[j];
        Vl[(wv * 16 + 8 + j) * 72 + m] = v1[j];
    }
    __syncthreads();

    const int dd = tid >> 2;
    const int oc = tid & 3;
    uint4 w0 = *(const uint4*)&Vl[dd * 72 + oc * 16];
    uint4 w1 = *(const uint4*)&Vl[dd * 72 + oc * 16 + 8];
    short* dst = vtp + (size_t)bh * (64 * 2048) + (size_t)dd * 2048 + t0 + oc * 16;
    *(uint4*)(dst) = w0;
    *(uint4*)(dst + 8) = w1;
}

// ---------------------------------------------------------------------------
// Flash attention v6.
//  * 1024 blocks x 128 threads (2 waves): 8 blocks/CU, 16 waves/CU.
//  * wave owns 32 q-rows (2 sets of 16) sharing all K/V fragment reads.
//  * K tiles: global_load_lds DMA, double-buffered, key-permutation and
//    XOR-chunk swizzle folded into the per-lane DMA source address ->
//    fragment ds_read_b128 conflict-free; exp'd S^T C-frags ARE the PV
//    A-frags (register P, r4-verified trick).
//  * V frags from global (L2-resident vtp), issued at iter start, consumed
//    after the S-phase (~600 cyc of cover).
//  * exp2-only softmax (Q pre-scaled in in_proj), perm-packed bf16.
// ---------------------------------------------------------------------------
__global__ __launch_bounds__(128, 4)
void attn_mfma(const short* __restrict__ qkv, const short* __restrict__ vtp,
               short* __restrict__ ctxh, short* __restrict__ ctxl)
{
    __shared__ __align__(16) short Ks[2][64 * 64];
    __shared__ float Ls[2][32];

    const int tid  = threadIdx.x;
    const int lane = tid & 63;
    const int wave = tid >> 6;
    const int fr = lane & 15;
    const int g  = lane >> 4;

    // XCD-aware decode: 8 XCD groups x 4 bh x 32 q-tiles(64 rows)
    const int id   = blockIdx.x;
    const int slot = id >> 3;
    const int bh   = (id & 7) * 4 + (slot & 3);
    const int q0   = (slot >> 2) * 64;
    const int b = bh >> 4, h = bh & 15;

    // ---- K DMA per-lane source offsets (permuted + chunk-swizzled) ----
    // LDS row R holds key K(R) = bits [r5, r3, r2, r4, r1, r0]; chunk at
    // slot (lane&7) is global chunk (lane&7)^(row&7).
    const int chunk = (lane & 7) ^ ((lane >> 3) & 7);
    int koff[4];
    #pragma unroll
    for (int i = 0; i < 4; ++i) {
        int row = wave * 32 + i * 8 + (lane >> 3);
        int kk = (row & 32) | ((row & 12) << 1) | ((row & 16) >> 2) | (row & 3);
        koff[i] = (kk * 2 + b) * 3072 + h * 192 + 64 + chunk * 8;
    }

    // ---- Q fragments (pre-scaled by QK_SCALE in in_proj) ----
    short8 aq[2][2];
    #pragma unroll
    for (int set = 0; set < 2; ++set) {
        const short* qrow = qkv +
            ((size_t)(q0 + wave * 32 + set * 16 + fr) * 2 + b) * 3072 + h * 192;
        aq[set][0] = *(const short8*)(qrow + g * 8);
        aq[set][1] = *(const short8*)(qrow + 32 + g * 8);
    }

    // ---- V per-lane offsets ----
    const short* vbase = vtp + (size_t)bh * (64 * 2048);
    int voff[4];
    #pragma unroll
    for (int jd = 0; jd < 4; ++jd) voff[jd] = (16 * jd + fr) * 2048 + g * 8;

    const f32x4 zero = {0.f, 0.f, 0.f, 0.f};
    f32x4 o[2][4];
    #pragma unroll
    for (int set = 0; set < 2; ++set)
        #pragma unroll
        for (int jd = 0; jd < 4; ++jd) o[set][jd] = zero;
    float lsum[2] = {0.f, 0.f};

    // ---- pre-loop: DMA K tile 0 into buf 0 ----
    #pragma unroll
    for (int i = 0; i < 4; ++i)
        gl2lds16(qkv + koff[i], &Ks[0][(wave * 4 + i) * 512]);

    const int slot0 = (g ^ (fr & 7)) * 8;
    const int slot1 = ((g + 4) ^ (fr & 7)) * 8;

    for (int s0 = 0; s0 < T_DIM; s0 += 64) {
        const int p = (s0 >> 6) & 1;
        __syncthreads();   // buf p DMA complete (vmcnt drain); prev reads done

        // V frags for THIS tile: consumed after S-phase (latency covered)
        short8 bv0[4], bv1[4];
        #pragma unroll
        for (int jd = 0; jd < 4; ++jd) {
            const short* vr = vbase + voff[jd] + s0;
            bv0[jd] = *(const short8*)vr;
            bv1[jd] = *(const short8*)(vr + 32);
        }
        // DMA NEXT K tile into buf p^1 (all waves past barrier => safe)
        if (s0 + 64 < T_DIM) {
            const short* kb = qkv + (size_t)(s0 + 64) * 6144;
            #pragma unroll
            for (int i = 0; i < 4; ++i)
                gl2lds16(kb + koff[i], &Ks[p ^ 1][(wave * 4 + i) * 512]);
        }

        // ---- S^T = K Q^T, exp2, perm-pack -> register A-frags ----
        int afw[2][2][4];   // [set][half][word]
        #pragma unroll
        for (int s = 0; s < 4; ++s) {
            const short* kr = &Ks[p][(16 * s + fr) * 64];
            short8 bk0 = *(const short8*)(kr + slot0);
            short8 bk1 = *(const short8*)(kr + slot1);
            #pragma unroll
            for (int set = 0; set < 2; ++set) {
                f32x4 a = zero;
                a = mfma_bf16(bk0, aq[set][0], a);
                a = mfma_bf16(bk1, aq[set][1], a);
                float e0 = EXP2F(a[0]), e1 = EXP2F(a[1]);
                float e2 = EXP2F(a[2]), e3 = EXP2F(a[3]);
                lsum[set] += (e0 + e1) + (e2 + e3);
                afw[set][s >> 1][(s & 1) * 2]     = pack_bf16(e1, e0);
                afw[set][s >> 1][(s & 1) * 2 + 1] = pack_bf16(e3, e2);
            }
        }

        // ---- O += P V (register P, prefetched V) ----
        #pragma unroll
        for (int set = 0; set < 2; ++set) {
            union { int w[4]; short8 v; } A0, A1;
            #pragma unroll
            for (int w = 0; w < 4; ++w) { A0.w[w] = afw[set][0][w]; A1.w[w] = afw[set][1][w]; }
            #pragma unroll
            for (int jd = 0; jd < 4; ++jd) {
                o[set][jd] = mfma_bf16(A0.v, bv0[jd], o[set][jd]);
                o[set][jd] = mfma_bf16(A1.v, bv1[jd], o[set][jd]);
            }
        }
    }

    // ---- finalize l: combine 4 g-partials per q-column ----
    #pragma unroll
    for (int set = 0; set < 2; ++set) {
        lsum[set] += __shfl_xor(lsum[set], 16);
        lsum[set] += __shfl_xor(lsum[set], 32);
        Ls[wave][set * 16 + fr] = lsum[set];
    }
    __builtin_amdgcn_s_waitcnt(0xc07f);   // lgkmcnt(0): wave-private Ls visible

    // ---- epilogue: normalize, split hi/lo, store ctx ----
    #pragma unroll
    for (int set = 0; set < 2; ++set)
        #pragma unroll
        for (int r = 0; r < 4; ++r) {
            float inv = 1.f / Ls[wave][set * 16 + 4 * g + r];
            int t = q0 + wave * 32 + set * 16 + 4 * g + r;
            size_t base = ((size_t)t * B_DIM + b) * E_DIM + h * 64;
            #pragma unroll
            for (int jd = 0; jd < 4; ++jd) {
                float v = o[set][jd][r] * inv;
                short hs = f2bf(v);
                short ls = f2bf(v - bf2f(hs));
                ctxh[base + 16 * jd + fr] = hs;
                ctxl[base + 16 * jd + fr] = ls;
            }
        }
}

// ---------------------------------------------------------------------------
extern "C" void kernel_launch(void* const* d_in, const int* in_sizes, int n_in,
                              void* d_out, int out_size, void* d_ws, size_t ws_size,
                              hipStream_t stream)
{
    const float* query = (const float*)d_in[0];
    const float* w_in  = (const float*)d_in[1];
    const float* b_in  = (const float*)d_in[2];
    const float* w_out = (const float*)d_in[3];
    const float* b_out = (const float*)d_in[4];
    float* out = (float*)d_out;

    char* ws = (char*)d_ws;
    short* qkv  = (short*)(ws);                  // 25.2 MB
    short* qh   = (short*)(ws + 25165824);       // 8.4 MB
    short* wih  = (short*)(ws + 33554432);       // 6.3 MB
    short* wil  = (short*)(ws + 39845888);       // 6.3 MB
    short* woh  = (short*)(ws + 46137344);       // 2.1 MB
    short* wol  = (short*)(ws + 48234496);       // 2.1 MB
    short* vtp  = (short*)(ws + 50331648);       // 8.4 MB  V^T [bh][d][t]
    short* ctxh = (short*)(ws + 25165824);       // alias qh  (dead after in_proj)
    short* ctxl = (short*)(ws + 33554432);       // alias wih (dead after in_proj)

    const int M = T_DIM * B_DIM;  // 4096

    int nq4  = (M * E_DIM) / 4;            // 1048576
    int nwi4 = (3 * E_DIM * E_DIM) / 4;    // 786432
    int nwo4 = (E_DIM * E_DIM) / 4;        // 262144
    split_all_kernel<<<(nq4 + nwi4 + nwo4) / 256, 256, 0, stream>>>(
        query, w_in, w_out, qh, wih, wil, woh, wol, nq4, nwi4, nwo4);

    // in_proj: qkv_bf16 = q @ w_in^T + b_in (w-split, 2 MFMA), q-cols pre-scaled
    gemm_mfma<false, true, true><<<dim3(3 * E_DIM / 128, M / 128), 256, 0, stream>>>(
        qh, qh, wih, wil, b_in, qkv, M, 3 * E_DIM, E_DIM);

    // one-shot V transpose into [bh][d][t]
    repack_vt<<<dim3(T_DIM / 64, 32), 256, 0, stream>>>(qkv, vtp);

    // attention: 1024 blocks x 128 threads
    attn_mfma<<<dim3(1024), 128, 0, stream>>>(qkv, vtp, ctxh, ctxl);

    // out_proj: out = ctx @ w_out^T + b_out (full split, 3 MFMA)
    gemm_mfma<true, false, false><<<dim3(E_DIM / 128, M / 128), 256, 0, stream>>>(
        ctxh, ctxl, woh, wol, b_out, out, M, E_DIM, E_DIM);
}